// Round 4
// baseline (503.317 us; speedup 1.0000x reference)
//
#include <hip/hip_runtime.h>
#include <hip/hip_bf16.h>

// CGCNN: B=16, N=1024, M=12, F=64, BF=128, 3 conv layers.
// bond is layer-invariant -> ONE bf16 MFMA GEMM produces core+filt for all
// 3 layers. Per-layer: atomproj_mfma (x @ [w1|w2|fw1|fw2], split-bf16)
// + light gather epilogue (layer_ep).
//
// R3: single 16-row fragment/wave gemm (spill-free), atomproj via MFMA.
// R4: gemm_bond was latency-bound (all pipes <7%, 8 waves/CU): block=1024
//     (16 waves) x grid=256 (1 block/CU) -> 16 waves/CU sharing ONE LDS
//     panel; staging is 4 float4/thread (no prologue spill). prep kernels
//     + embed merged into prep_all. layer_ep: 4 rows/wave, unroll 2.

#define BB 16
#define NN 1024
#define MM 12
#define FF 64
#define BFE 128
#define RT (BB * NN * MM)   // 196608 bond rows
#define S_BN 0.99950037f    // 1/sqrt(1+1e-3)
#define WCOLS 208           // 192 core cols (3 layers x 64) + 3 filt + 13 pad
#define WSTR 136            // padded K stride (bf16) for bond GEMM panel
#define PCOLS 144           // atomproj panel: 64 w1 + 64 w2 + fw1 + fw2 + pad
#define PSTR 72             // padded K stride (bf16) for atomproj panel
#define PSZ (PCOLS * PSTR)  // 10368 shorts per (hi|lo) panel

#define N_EMB (BB * NN * FF)        // 1048576
#define N_FOLD 192
#define N_WT (WCOLS * WSTR)         // 28288
#define N_WPROJ (3 * PSZ)           // 31104
#define N_PREP (N_EMB + N_FOLD + N_WT + N_WPROJ)

typedef __attribute__((ext_vector_type(8))) short bf16x8;
typedef __attribute__((ext_vector_type(4))) float f32x4;

static __device__ __forceinline__ unsigned short f2bf(float f) {
    union { float f; unsigned u; } c; c.f = f;
    unsigned r = c.u + 0x7fff + ((c.u >> 16) & 1);   // RNE
    return (unsigned short)(r >> 16);
}
static __device__ __forceinline__ float bf2f(unsigned short s) {
    union { unsigned u; float f; } c; c.u = ((unsigned)s) << 16;
    return c.f;
}
static __device__ __forceinline__ bf16x8 pack_bf16x8(float4 a, float4 b) {
    union { unsigned u[4]; bf16x8 v; } r;
    r.u[0] = (unsigned)f2bf(a.x) | ((unsigned)f2bf(a.y) << 16);
    r.u[1] = (unsigned)f2bf(a.z) | ((unsigned)f2bf(a.w) << 16);
    r.u[2] = (unsigned)f2bf(b.x) | ((unsigned)f2bf(b.y) << 16);
    r.u[3] = (unsigned)f2bf(b.z) | ((unsigned)f2bf(b.w) << 16);
    return r.v;
}
static __device__ __forceinline__ float4 residual4(float4 v) {
    float4 r;
    r.x = v.x - bf2f(f2bf(v.x));
    r.y = v.y - bf2f(f2bf(v.y));
    r.z = v.z - bf2f(f2bf(v.z));
    r.w = v.w - bf2f(f2bf(v.w));
    return r;
}

// ---- all preprocessing in one launch ---------------------------------------
// ranges: [0,N_EMB) embedding gather -> x
//         [N_EMB, +192) fold BN-a into core bias cbp
//         [.., +28288) bond-GEMM weight panel wT (permuted cols, bf16)
//         [.., +31104) atomproj hi/lo split-bf16 panels wproj
__global__ void prep_all(const int* __restrict__ at, const float* __restrict__ emb,
                         const float* __restrict__ cw, const float* __restrict__ cb,
                         const float* __restrict__ fw, const float* __restrict__ g,
                         const float* __restrict__ bab,
                         float* __restrict__ x, float* __restrict__ cbp,
                         unsigned short* __restrict__ wT,
                         unsigned short* __restrict__ wproj) {
    int i = blockIdx.x * 256 + threadIdx.x;
    if (i < N_EMB) {
        x[i] = emb[at[i >> 6] * FF + (i & 63)];
        return;
    }
    i -= N_EMB;
    if (i < N_FOLD) {
        int f = i & 63, l = i >> 6;
        float gs = g[l * 64 + f] * S_BN;
        cbp[i] = cb[l * 64 + f] * gs + bab[l * 64 + f];
        return;
    }
    i -= N_FOLD;
    if (i < N_WT) {
        int col = i / WSTR, k = i % WSTR;
        float v = 0.f;
        if (k < 128) {
            if (col < 192) {
                int l = col >> 6, p = col & 63;
                int f = ((p & 15) << 2) | (p >> 4);       // 4*m + tt
                v = cw[(l * 256 + 128 + k) * 64 + f] * g[l * 64 + f] * S_BN;
            } else if (col < 195) {
                int l = col - 192;
                v = fw[l * 256 + 128 + k];
            }
        }
        wT[i] = f2bf(v);
        return;
    }
    i -= N_WT;
    if (i < N_WPROJ) {
        int l = i / PSZ;
        int rem = i % PSZ;
        int col = rem / PSTR, k = rem % PSTR;
        float v = 0.f;
        if (k < 64) {
            if (col < 64)
                v = cw[(l * 256 + k) * 64 + col] * g[l * 64 + col] * S_BN;
            else if (col < 128)
                v = cw[(l * 256 + 64 + k) * 64 + (col - 64)] * g[l * 64 + (col - 64)] * S_BN;
            else if (col == 128)
                v = fw[l * 256 + k];
            else if (col == 129)
                v = fw[l * 256 + 64 + k];
        }
        unsigned short hi = f2bf(v);
        wproj[(size_t)l * 2 * PSZ + col * PSTR + k] = hi;
        wproj[(size_t)l * 2 * PSZ + PSZ + col * PSTR + k] = f2bf(v - bf2f(hi));
    }
}

// ---- one-shot bf16 MFMA GEMM: core_{0,1,2} (bf16) + filt_{0,1,2} (fp32) ----
// A = bond (196608 x 128, fp32 -> bf16 in registers), B = wT (128 x 208)
// 256 blocks (1/CU) x 1024 threads (16 waves/CU) x 3 passes x 256 rows.
// Weights staged once per block; barrier-free main loop; ~90 live VGPRs.
__global__ __launch_bounds__(1024, 4) void gemm_bond(
    const float* __restrict__ bond, const unsigned short* __restrict__ wT,
    unsigned short* __restrict__ core, float* __restrict__ filt) {
    __shared__ unsigned short bsh[WCOLS * WSTR];  // 56576 B weights
    int tid = threadIdx.x;
    int wv = tid >> 6, lane = tid & 63;
    int m = lane & 15, quad = lane >> 4;

    // stage weights ONCE (3536 float4, 4 per thread)
    const float4* wsrc = (const float4*)wT;
    float4* wdst = (float4*)bsh;
    #pragma unroll
    for (int i = 0; i < 4; i++) {
        int idx = tid + 1024 * i;
        if (idx < (WCOLS * WSTR * 2) / 16) wdst[idx] = wsrc[idx];
    }
    __syncthreads();

    #pragma unroll 1
    for (int it = 0; it < 3; it++) {
        int row0 = blockIdx.x * 768 + it * 256;
        const float* abase = bond + (size_t)(row0 + wv * 16 + m) * BFE + quad * 8;

        bf16x8 af[4];
        #pragma unroll
        for (int c = 0; c < 4; c++) {
            float4 v0 = *(const float4*)(abase + c * 32);
            float4 v1 = *(const float4*)(abase + c * 32 + 4);
            af[c] = pack_bf16x8(v0, v1);
        }

        f32x4 acc[13];
        #pragma unroll
        for (int t = 0; t < 13; t++) acc[t] = (f32x4){0.f, 0.f, 0.f, 0.f};

        #pragma unroll
        for (int c = 0; c < 4; c++) {
            bf16x8 a = af[c];
            #pragma unroll
            for (int t = 0; t < 13; t++) {
                bf16x8 bfv = *(const bf16x8*)&bsh[(t * 16 + m) * WSTR + c * 32 + quad * 8];
                acc[t] = __builtin_amdgcn_mfma_f32_16x16x32_bf16(a, bfv, acc[t], 0, 0, 0);
            }
        }

        int crow = row0 + wv * 16 + quad * 4;
        #pragma unroll
        for (int l = 0; l < 3; l++) {
            #pragma unroll
            for (int r = 0; r < 4; r++) {
                ushort4 h;
                h.x = f2bf(acc[l * 4 + 0][r]);
                h.y = f2bf(acc[l * 4 + 1][r]);
                h.z = f2bf(acc[l * 4 + 2][r]);
                h.w = f2bf(acc[l * 4 + 3][r]);
                *(ushort4*)&core[((size_t)l * RT + crow + r) * 64 + 4 * m] = h;
            }
        }
        if (m < 3) {
            #pragma unroll
            for (int r = 0; r < 4; r++)
                filt[(size_t)m * RT + crow + r] = acc[12][r];
        }
    }
}

// ---- per-atom projections via MFMA (hi/lo split-bf16, ~f32 accuracy) -------
// C = x (16384x64) @ panel (64x144): cols 0..63 ys (+bias), 64..127 yn,
// 128 fs-proj (+fb), 129 fn-proj. acc = Ahi*Bhi + Alo*Bhi + Ahi*Blo.
__global__ __launch_bounds__(256) void atomproj_mfma(
    const float* __restrict__ x, const unsigned short* __restrict__ wproj_l,
    const float* __restrict__ cbp_l, const float* __restrict__ fb_l,
    float* __restrict__ ys, float* __restrict__ yn,
    float* __restrict__ fs, float* __restrict__ fn) {
    __shared__ unsigned short psh[2 * PSZ];   // 41472 B: hi panel then lo panel
    int tid = threadIdx.x, w = tid >> 6, lane = tid & 63;
    int m = lane & 15, quad = lane >> 4;

    const float4* src = (const float4*)wproj_l;
    float4* dst = (float4*)psh;
    #pragma unroll
    for (int i = 0; i < 11; i++) {
        int idx = tid + 256 * i;
        if (idx < (2 * PSZ * 2) / 16) dst[idx] = src[idx];
    }
    __syncthreads();

    int row = blockIdx.x * 64 + w * 16 + m;
    const float* xb = x + (size_t)row * 64 + quad * 8;
    bf16x8 ahi[2], alo[2];
    #pragma unroll
    for (int c = 0; c < 2; c++) {
        float4 v0 = *(const float4*)(xb + c * 32);
        float4 v1 = *(const float4*)(xb + c * 32 + 4);
        ahi[c] = pack_bf16x8(v0, v1);
        alo[c] = pack_bf16x8(residual4(v0), residual4(v1));
    }

    f32x4 acc[9];
    #pragma unroll
    for (int t = 0; t < 9; t++) acc[t] = (f32x4){0.f, 0.f, 0.f, 0.f};

    #pragma unroll
    for (int c = 0; c < 2; c++) {
        #pragma unroll
        for (int t = 0; t < 9; t++) {
            int off = (t * 16 + m) * PSTR + c * 32 + quad * 8;
            bf16x8 bh = *(const bf16x8*)&psh[off];
            bf16x8 bl = *(const bf16x8*)&psh[PSZ + off];
            acc[t] = __builtin_amdgcn_mfma_f32_16x16x32_bf16(ahi[c], bh, acc[t], 0, 0, 0);
            acc[t] = __builtin_amdgcn_mfma_f32_16x16x32_bf16(alo[c], bh, acc[t], 0, 0, 0);
            acc[t] = __builtin_amdgcn_mfma_f32_16x16x32_bf16(ahi[c], bl, acc[t], 0, 0, 0);
        }
    }

    int crow = blockIdx.x * 64 + w * 16 + quad * 4;
    #pragma unroll
    for (int t = 0; t < 4; t++) {
        float bias = cbp_l[t * 16 + m];
        #pragma unroll
        for (int r = 0; r < 4; r++)
            ys[(size_t)(crow + r) * 64 + t * 16 + m] = acc[t][r] + bias;
    }
    #pragma unroll
    for (int t = 4; t < 8; t++) {
        #pragma unroll
        for (int r = 0; r < 4; r++)
            yn[(size_t)(crow + r) * 64 + (t - 4) * 16 + m] = acc[t][r];
    }
    if (m == 0) {
        float fbv = fb_l[0];
        #pragma unroll
        for (int r = 0; r < 4; r++) fs[crow + r] = acc[8][r] + fbv;
    }
    if (m == 1) {
        #pragma unroll
        for (int r = 0; r < 4; r++) fn[crow + r] = acc[8][r];
    }
}

// ---- per-layer epilogue: softmax + weighted mean + BN-b + residual ---------
// 4 rows per wave (independent iterations -> pipelined gathers), grid 1024.
__global__ __launch_bounds__(256) void layer_ep(
    const float* __restrict__ x, const unsigned short* __restrict__ core_l,
    const float* __restrict__ filt_l, const int* __restrict__ nbr,
    const float* __restrict__ ys, const float* __restrict__ yn,
    const float* __restrict__ fs, const float* __restrict__ fn,
    const float* __restrict__ bbg, const float* __restrict__ bbb,
    float* __restrict__ xout) {
    int tid = threadIdx.x, w = tid >> 6, lane = tid & 63;
    float bg = bbg[lane], bb = bbb[lane];
    #pragma unroll 2
    for (int rr = 0; rr < 4; rr++) {
        int row = blockIdx.x * 16 + w * 4 + rr;
        int base = (row >> 10) * NN;
        size_t rb = (size_t)row * MM;

        int jv[MM]; float fltv[MM], corev[MM];
        #pragma unroll
        for (int mm = 0; mm < MM; mm++) jv[mm] = nbr[rb + mm];
        float fsv = fs[row], ysv = ys[(size_t)row * 64 + lane];
        #pragma unroll
        for (int mm = 0; mm < MM; mm++)
            fltv[mm] = filt_l[rb + mm] + fsv + fn[base + jv[mm]];
        #pragma unroll
        for (int mm = 0; mm < MM; mm++)
            corev[mm] = bf2f(core_l[(rb + mm) * 64 + lane]) + ysv
                      + yn[(size_t)(base + jv[mm]) * 64 + lane];
        float fmax = -1e30f;
        #pragma unroll
        for (int mm = 0; mm < MM; mm++) fmax = fmaxf(fmax, fltv[mm]);
        float fsum = 0.f;
        #pragma unroll
        for (int mm = 0; mm < MM; mm++) { fltv[mm] = __expf(fltv[mm] - fmax); fsum += fltv[mm]; }
        float inv = 1.f / (12.f * fsum);
        float summed = 0.f;
        #pragma unroll
        for (int mm = 0; mm < MM; mm++) summed += fltv[mm] * fmaxf(corev[mm], 0.f);
        summed *= inv;
        float o = x[(size_t)row * 64 + lane] + bg * (summed * S_BN) + bb;
        xout[(size_t)row * 64 + lane] = fmaxf(o, 0.f);
    }
}

// ---- pooling gather + dense + relu ----------------------------------------
__global__ __launch_bounds__(256) void final_k(
    const float* __restrict__ x, const int* __restrict__ tidx,
    const float* __restrict__ dw, const float* __restrict__ db,
    float* __restrict__ out) {
    __shared__ float xs[4][64];
    __shared__ float wsh[64 * 64];
    int tid = threadIdx.x;
    int w = tid >> 6, lane = tid & 63;
    const float4* src = (const float4*)dw;
    float4* dst = (float4*)wsh;
    #pragma unroll
    for (int i = 0; i < 4; i++) dst[tid + 256 * i] = src[tid + 256 * i];
    int row = blockIdx.x * 4 + w;        // b*64 + i
    int b = row >> 6;
    int t = tidx[row];
    float xv = x[((size_t)b * NN + t) * 64 + lane];
    xs[w][lane] = fmaxf(xv, 0.f);
    __syncthreads();
    float a = db[lane];
    #pragma unroll 16
    for (int k = 0; k < 64; k++) a += xs[w][k] * wsh[k * 64 + lane];
    out[row * 64 + lane] = fmaxf(a, 0.f);
}

extern "C" void kernel_launch(void* const* d_in, const int* in_sizes, int n_in,
                              void* d_out, int out_size, void* d_ws, size_t ws_size,
                              hipStream_t stream) {
    const int*   at   = (const int*)d_in[0];
    const float* bond = (const float*)d_in[1];
    const int*   nbr  = (const int*)d_in[2];
    const int*   tgt  = (const int*)d_in[3];
    const float* emb  = (const float*)d_in[4];
    const float* cw   = (const float*)d_in[5];
    const float* cb   = (const float*)d_in[6];
    const float* fw   = (const float*)d_in[7];
    const float* fb   = (const float*)d_in[8];
    const float* bag  = (const float*)d_in[9];
    const float* bab  = (const float*)d_in[10];
    const float* bbg  = (const float*)d_in[11];
    const float* bbb  = (const float*)d_in[12];
    const float* dw   = (const float*)d_in[13];
    const float* db   = (const float*)d_in[14];

    float* ws   = (float*)d_ws;
    float* xA   = ws;
    float* xB   = xA + (size_t)BB * NN * FF;          // 1,048,576 each
    float* cwp  = xB + (size_t)BB * NN * FF;          // 49,152 (reused as wproj)
    float* cbp  = cwp + 3 * 256 * 64;                 // 192
    float* ys   = cbp + 192;                          // 1,048,576
    float* yn   = ys + (size_t)BB * NN * FF;          // 1,048,576
    float* fs   = yn + (size_t)BB * NN * FF;          // 16,384
    float* fn   = fs + (size_t)BB * NN;               // 16,384
    float* filt = fn + (size_t)BB * NN;               // 3*196608 fp32
    unsigned short* wT   = (unsigned short*)(filt + 3 * (size_t)RT);  // 28,288 bf16
    unsigned short* core = wT + WCOLS * WSTR;         // 3*196608*64 bf16 (~75.5 MB)
    unsigned short* wproj = (unsigned short*)cwp;     // 62,208 shorts (fits 49,152 f32)
    // total ~95 MB (unchanged)

    prep_all<<<(N_PREP + 255) / 256, 256, 0, stream>>>(
        at, emb, cw, cb, fw, bag, bab, xA, cbp, wT, wproj);
    gemm_bond<<<256, 1024, 0, stream>>>(bond, wT, core, filt);

    float* xin = xA;
    float* xout = xB;
    for (int l = 0; l < 3; l++) {
        atomproj_mfma<<<BB * NN / 64, 256, 0, stream>>>(
            xin, wproj + (size_t)l * 2 * PSZ, cbp + l * 64, fb + l,
            ys, yn, fs, fn);
        layer_ep<<<BB * NN / 16, 256, 0, stream>>>(
            xin, core + (size_t)l * RT * 64, filt + (size_t)l * RT, nbr,
            ys, yn, fs, fn, bbg + l * 64, bbb + l * 64, xout);
        float* t = xin; xin = xout; xout = t;
    }

    final_k<<<BB * 64 / 4, 256, 0, stream>>>(xin, tgt, dw, db, (float*)d_out);
}